// Round 7
// baseline (5033.070 us; speedup 1.0000x reference)
//
#include <hip/hip_runtime.h>
#include <hip/hip_bf16.h>

// ---------------------------------------------------------------------------
// LIIF query_image fused kernel for MI355X (gfx950).  Round 6 (resubmit - R6
// never ran: GPU acquisition timeout).
// Split-precision bf16 MFMA (hi/lo, 3 products) ~= fp32 accuracy.
// R6 vs R5: (1) amdgpu_waves_per_eu(2,2) -> compiler sees the true 2-wave/EU
// occupancy (dynamic LDS hid it) -> 256-VGPR budget, no spill; (2) 2-deep
// software pipeline for global B-loads with NAMED register sets (bhA/bhB,
// unroll-by-2, all indices compile-time -> no scratch arrays).
// ---------------------------------------------------------------------------

typedef __attribute__((ext_vector_type(8)))  short   short8_t;
typedef __attribute__((ext_vector_type(8)))  __bf16  bf16x8;
typedef __attribute__((ext_vector_type(16))) float   f32x16;
typedef __attribute__((ext_vector_type(4)))  float   float4_t;

union Frag8 { short8_t s; bf16x8 b; };

#define EPS_SHIFT 1e-6f
#define EPS_AREA  1e-9f

constexpr int Bc = 2, Cc = 128, Hc = 128, Wc = 128, HLc = 64, WLc = 64;
constexpr int K0P = 272;          // layer0 K padded: 262 -> 272 (17 k-chunks of 16)
constexpr int TM = 128;           // queries per block
constexpr int THREADS = 512;      // 8 waves: 2(M) x 4(N)
constexpr int NKB = K0P / 8;      // 34 k-blocks of 8 in act buffer
constexpr int KBS = TM * 16;      // 2048 B per k-block per plane
constexpr int PLANE = NKB * KBS;  // 69632 B  (hi plane; lo plane follows)
constexpr int LDS_WT = 2 * PLANE;              // offset of weight table
constexpr int LDS_TOTAL = LDS_WT + 4 * TM * 4; // + wtab[4][128] = 141312 B

// workspace layout
constexpr size_t OFF_FEATT = 0;
constexpr size_t SZ_FEATT  = (size_t)Bc * Hc * Wc * Cc * 4;    // 16 MB
constexpr size_t OFF_LRT   = OFF_FEATT + SZ_FEATT;
constexpr size_t SZ_LRT    = (size_t)Bc * HLc * WLc * Cc * 4;  // 4 MB
constexpr size_t OFF_WT0   = OFF_LRT + SZ_LRT;
constexpr size_t PS0       = (size_t)256 * K0P * 2;            // per-plane bytes
constexpr size_t OFF_WT1   = OFF_WT0 + 2 * PS0;
constexpr size_t PS1       = (size_t)256 * 256 * 2;
constexpr size_t OFF_WT2   = OFF_WT1 + 2 * PS1;
constexpr size_t OFF_WT3   = OFF_WT2 + 2 * PS1;
constexpr size_t OFF_WT4   = OFF_WT3 + 2 * PS1;
constexpr size_t PS4       = (size_t)32 * 256 * 2;

// ---------------------------------------------------------------------------

__device__ __forceinline__ unsigned short bf16_rne(float x) {
    unsigned u = __float_as_uint(x);
    unsigned r = (u + 0x7FFFu + ((u >> 16) & 1u)) >> 16;
    return (unsigned short)r;
}

// x = hi + lo + eps, |eps| ~ 2^-17 |x|.  hi = truncated bf16, lo = rne(bf16(rem)).
__device__ __forceinline__ void split2(float v, unsigned short& hi, unsigned short& lo) {
    unsigned u = __float_as_uint(v) & 0xFFFF0000u;
    hi = (unsigned short)(u >> 16);
    lo = bf16_rne(v - __uint_as_float(u));
}

// byte offset of the 8-k group (row, kb) inside a plane (swizzled)
__device__ __forceinline__ int lds_grp(int row, int kb) {
    return kb * KBS + ((row * 16) ^ ((kb & 7) << 4));
}

// nearest-gather index math, exactly mirroring the reference formulas
__device__ __forceinline__ void calc_idx(float c0, float c1, int s,
                                         int& iy, int& ix, int& liy, int& lix,
                                         float& rel0, float& rel1) {
    const float rx = 1.0f / Hc, ry = 1.0f / Wc;
    const float vx = (s & 2) ? 1.0f : -1.0f;   // s: 0..3 = (vx,vy) in (-1,-1),(-1,1),(1,-1),(1,1)
    const float vy = (s & 1) ? 1.0f : -1.0f;
    const float sh0 = vx * rx + EPS_SHIFT;
    const float sh1 = vy * ry + EPS_SHIFT;
    float cc0 = fminf(fmaxf(c0 + sh0, -1.0f + 1e-6f), 1.0f - 1e-6f);
    float cc1 = fminf(fmaxf(c1 + sh1, -1.0f + 1e-6f), 1.0f - 1e-6f);
    iy  = min(max((int)floorf(((cc0 + 1.0f) * (float)Hc  - 1.0f) * 0.5f + 0.5f), 0), Hc  - 1);
    ix  = min(max((int)floorf(((cc1 + 1.0f) * (float)Wc  - 1.0f) * 0.5f + 0.5f), 0), Wc  - 1);
    liy = min(max((int)floorf(((cc0 + 1.0f) * (float)HLc - 1.0f) * 0.5f + 0.5f), 0), HLc - 1);
    lix = min(max((int)floorf(((cc1 + 1.0f) * (float)WLc - 1.0f) * 0.5f + 0.5f), 0), WLc - 1);
    const float qc0 = -1.0f + (2.0f * (float)iy + 1.0f) / (float)Hc;
    const float qc1 = -1.0f + (2.0f * (float)ix + 1.0f) / (float)Wc;
    rel0 = (c0 - qc0) * (float)Hc;   // rel uses ORIGINAL coord
    rel1 = (c1 - qc1) * (float)Wc;
}

template <bool NT>
__device__ __forceinline__ float4_t ld4(const float* p) {
    if (NT) return __builtin_nontemporal_load(reinterpret_cast<const float4_t*>(p));
    return *reinterpret_cast<const float4_t*>(p);
}

// gather 32 contiguous channels (NHWC) -> hi/lo planes at k-blocks kbBase..+3
template <bool NT>
__device__ __forceinline__ void gather_write(const float* __restrict__ src,
                                             char* sm, int row, int kbBase) {
    #pragma unroll
    for (int g = 0; g < 4; ++g) {
        float4_t v0 = ld4<NT>(src + g * 8);
        float4_t v1 = ld4<NT>(src + g * 8 + 4);
        short8_t h8, l8;
        #pragma unroll
        for (int j = 0; j < 4; ++j) {
            unsigned short hh, ll; split2(v0[j], hh, ll);
            h8[j] = (short)hh; l8[j] = (short)ll;
        }
        #pragma unroll
        for (int j = 0; j < 4; ++j) {
            unsigned short hh, ll; split2(v1[j], hh, ll);
            h8[4 + j] = (short)hh; l8[4 + j] = (short)ll;
        }
        const int off = lds_grp(row, kbBase + g);
        *reinterpret_cast<short8_t*>(sm + off)         = h8;
        *reinterpret_cast<short8_t*>(sm + PLANE + off) = l8;
    }
}

// one hidden layer: acc[M 2x32][N 2x32] = act(LDS) @ Wt + bias, split-bf16 x3.
// Global B-loads software-pipelined 1 kc ahead with NAMED register sets.
// Weights fragment-packed: frag byte offset = ((g*NKC+kc)*64+lane)*16.
template <int NKC>
__device__ __forceinline__ void layer_mfma(const char* sm, int lane, int rbase, int wn,
                                           const unsigned short* __restrict__ wHp,
                                           const unsigned short* __restrict__ wLp,
                                           const float* __restrict__ bias,
                                           f32x16 acc[2][2]) {
    const int rl = lane & 31, h = lane >> 5;
    #pragma unroll
    for (int ni = 0; ni < 2; ++ni) {
        const float bv = bias[wn * 64 + ni * 32 + rl];
        f32x16 a;
        #pragma unroll
        for (int i = 0; i < 16; ++i) a[i] = bv;
        acc[0][ni] = a; acc[1][ni] = a;
    }

    auto loadB = [&](Frag8 (&bh)[2], Frag8 (&bl)[2], int kc) {
        #pragma unroll
        for (int ni = 0; ni < 2; ++ni) {
            const size_t wo = (size_t)(((wn * 2 + ni) * NKC + kc) * 64 + lane) * 8;
            bh[ni].s = *reinterpret_cast<const short8_t*>(wHp + wo);
            bl[ni].s = *reinterpret_cast<const short8_t*>(wLp + wo);
        }
    };
    auto mfmaK = [&](const Frag8 (&bh)[2], const Frag8 (&bl)[2], int kc) {
        const int kb = 2 * kc + h;
        Frag8 ah[2], al[2];
        #pragma unroll
        for (int mi = 0; mi < 2; ++mi) {
            const int off = lds_grp(rbase + mi * 32 + rl, kb);
            ah[mi].s = *reinterpret_cast<const short8_t*>(sm + off);
            al[mi].s = *reinterpret_cast<const short8_t*>(sm + PLANE + off);
        }
        __builtin_amdgcn_s_setprio(1);
        #pragma unroll
        for (int mi = 0; mi < 2; ++mi)
            #pragma unroll
            for (int ni = 0; ni < 2; ++ni) {
                acc[mi][ni] = __builtin_amdgcn_mfma_f32_32x32x16_bf16(ah[mi].b, bh[ni].b, acc[mi][ni], 0, 0, 0);
                acc[mi][ni] = __builtin_amdgcn_mfma_f32_32x32x16_bf16(ah[mi].b, bl[ni].b, acc[mi][ni], 0, 0, 0);
                acc[mi][ni] = __builtin_amdgcn_mfma_f32_32x32x16_bf16(al[mi].b, bh[ni].b, acc[mi][ni], 0, 0, 0);
            }
        __builtin_amdgcn_s_setprio(0);
    };

    Frag8 bhA[2], blA[2], bhB[2], blB[2];
    loadB(bhA, blA, 0);
    #pragma unroll
    for (int t = 0; t < NKC / 2; ++t) {
        loadB(bhB, blB, 2 * t + 1);          // prefetch kc+1 while computing kc
        mfmaK(bhA, blA, 2 * t);
        if (2 * t + 2 < NKC) loadB(bhA, blA, 2 * t + 2);
        mfmaK(bhB, blB, 2 * t + 1);
    }
    if (NKC & 1) mfmaK(bhA, blA, NKC - 1);   // NKC=17 epilogue (preloaded above)
}

// relu + split + store accumulators back into the (same) act buffer
__device__ __forceinline__ void store_act(char* sm, int lane, int rbase, int nb,
                                          const f32x16 acc[2][2]) {
    const int rl = lane & 31, h = lane >> 5;
    #pragma unroll
    for (int mi = 0; mi < 2; ++mi)
        #pragma unroll
        for (int ni = 0; ni < 2; ++ni) {
            const int k   = nb + ni * 32 + rl;   // output col -> next layer k
            const int kb  = k >> 3;
            const int sub = (k & 7) * 2;
            const int swz = (kb & 7) << 4;
            #pragma unroll
            for (int reg = 0; reg < 16; ++reg) {
                float v = fmaxf(acc[mi][ni][reg], 0.0f);   // ReLU (layers 0..3)
                const int row = rbase + mi * 32 + (reg & 3) + 8 * (reg >> 2) + 4 * h;
                const int off = kb * KBS + ((row * 16) ^ swz) + sub;
                unsigned short hh, ll; split2(v, hh, ll);
                *reinterpret_cast<unsigned short*>(sm + off)         = hh;
                *reinterpret_cast<unsigned short*>(sm + PLANE + off) = ll;
            }
        }
}

// ---------------------------------------------------------------------------

__global__ __launch_bounds__(THREADS)
__attribute__((amdgpu_waves_per_eu(2, 2)))
void liif_main(const float* __restrict__ coord, const float* __restrict__ cell,
               const char* __restrict__ ws,
               const float* __restrict__ b0, const float* __restrict__ b1,
               const float* __restrict__ b2, const float* __restrict__ b3,
               const float* __restrict__ b4, float* __restrict__ out) {
    extern __shared__ char sm[];
    const int tid  = threadIdx.x;
    const int lane = tid & 63;
    const int wid  = tid >> 6;
    const int wm   = wid >> 2, wn = wid & 3;      // 2(M) x 4(N) wave grid
    const int gq0  = blockIdx.x * TM;
    const int bb   = gq0 >> 16;                   // batch (Q = 65536)

    const float* featT = reinterpret_cast<const float*>(ws + OFF_FEATT);
    const float* lrT   = reinterpret_cast<const float*>(ws + OFF_LRT);
    const unsigned short* wt0H = reinterpret_cast<const unsigned short*>(ws + OFF_WT0);
    const unsigned short* wt0L = reinterpret_cast<const unsigned short*>(ws + OFF_WT0 + PS0);
    const unsigned short* wHl[3] = {
        reinterpret_cast<const unsigned short*>(ws + OFF_WT1),
        reinterpret_cast<const unsigned short*>(ws + OFF_WT2),
        reinterpret_cast<const unsigned short*>(ws + OFF_WT3)};
    const unsigned short* wLl[3] = {
        reinterpret_cast<const unsigned short*>(ws + OFF_WT1 + PS1),
        reinterpret_cast<const unsigned short*>(ws + OFF_WT2 + PS1),
        reinterpret_cast<const unsigned short*>(ws + OFF_WT3 + PS1)};
    const float* bls[3] = {b1, b2, b3};

    // ---- prologue: zero the K-pad block (kb 33) and build ensemble weights ----
    for (int i = tid; i < (KBS / 4) * 2; i += THREADS) {
        const int p = i / (KBS / 4);
        const int j = i - p * (KBS / 4);
        *reinterpret_cast<int*>(sm + p * PLANE + 33 * KBS + j * 4) = 0;
    }
    if (tid < TM) {
        const int gq = gq0 + tid;
        const float c0 = coord[2 * gq], c1 = coord[2 * gq + 1];
        float a[4];
        #pragma unroll
        for (int s = 0; s < 4; ++s) {
            int iy, ix, liy, lix; float r0, r1;
            calc_idx(c0, c1, s, iy, ix, liy, lix, r0, r1);
            a[s] = fabsf(r0 * r1) + EPS_AREA;
        }
        const float tot = a[0] + a[1] + a[2] + a[3];
        float* wtab = reinterpret_cast<float*>(sm + LDS_WT);
        #pragma unroll
        for (int s = 0; s < 4; ++s) wtab[s * TM + tid] = a[3 - s] / tot;  // diagonal swap
    }

    f32x16 oacc;
    #pragma unroll
    for (int i = 0; i < 16; ++i) oacc[i] = 0.0f;

    #pragma unroll 1
    for (int s = 0; s < 4; ++s) {
        if (s) __syncthreads();   // prev-shift layer-4 reads done before overwrite

        // ---- gather: build X tile (262-dim, reordered) in hi/lo planes ----
        {
            const int r = tid >> 2, p = tid & 3;   // 4 threads per row, 32 ch each
            const int gq = gq0 + r;
            const float c0 = coord[2 * gq], c1 = coord[2 * gq + 1];
            int iy, ix, liy, lix; float r0, r1;
            calc_idx(c0, c1, s, iy, ix, liy, lix, r0, r1);
            const float* fsrc = featT + (((size_t)(bb * Hc  + iy)  * Wc  + ix)  * Cc + p * 32);
            const float* lsrc = lrT   + (((size_t)(bb * HLc + liy) * WLc + lix) * Cc + p * 32);
            gather_write<true >(fsrc, sm, r, p * 4);      // q_feat  -> k 0..127 (nt: 16MB stream)
            gather_write<false>(lsrc, sm, r, 16 + p * 4); // lq_feat -> k 128..255 (L2-resident)
            if (tid < TM) {                               // extras  -> k 256..263 (kb 32)
                const int gq2 = gq0 + tid;
                const float d0 = coord[2 * gq2], d1 = coord[2 * gq2 + 1];
                int jy, jx, ljy, ljx; float s0, s1;
                calc_idx(d0, d1, s, jy, jx, ljy, ljx, s0, s1);
                float vals[8];
                vals[0] = s0;                                       // rel_coord h
                vals[1] = s1;                                       // rel_coord w
                vals[2] = -1.0f + (2.0f * (float)ljy + 1.0f) / (float)HLc;
                vals[3] = -1.0f + (2.0f * (float)ljx + 1.0f) / (float)WLc;
                vals[4] = cell[2 * gq2]     * (float)Hc;            // rel_cell h
                vals[5] = cell[2 * gq2 + 1] * (float)Wc;            // rel_cell w
                vals[6] = 0.0f; vals[7] = 0.0f;
                short8_t h8, l8;
                #pragma unroll
                for (int j = 0; j < 8; ++j) {
                    unsigned short hh, ll; split2(vals[j], hh, ll);
                    h8[j] = (short)hh; l8[j] = (short)ll;
                }
                const int off = 32 * KBS + tid * 16;  // kb=32 -> swizzle slot 0
                *reinterpret_cast<short8_t*>(sm + off)         = h8;
                *reinterpret_cast<short8_t*>(sm + PLANE + off) = l8;
            }
        }
        __syncthreads();

        // ---- layer 0 (K=272 padded) ----
        f32x16 acc[2][2];
        layer_mfma<17>(sm, lane, wm * 64, wn, wt0H, wt0L, b0, acc);
        __syncthreads();                 // all X reads complete
        store_act(sm, lane, wm * 64, wn * 64, acc);

        // ---- layers 1..3 (K=256) ----
        #pragma unroll
        for (int l = 0; l < 3; ++l) {
            __syncthreads();             // act writes visible
            layer_mfma<16>(sm, lane, wm * 64, wn, wHl[l], wLl[l], bls[l], acc);
            __syncthreads();
            store_act(sm, lane, wm * 64, wn * 64, acc);
        }
        __syncthreads();

        // ---- layer 4 (N=3 padded to 32): waves 0..3, one 32-row tile each ----
        if (wid < 4) {
            const int rl = lane & 31, h = lane >> 5;
            const int rb4 = wid * 32;
            const float bv = (rl < 3) ? b4[rl] : 0.0f;
            f32x16 p4;
            #pragma unroll
            for (int i = 0; i < 16; ++i) p4[i] = bv;
            const unsigned short* w4H = reinterpret_cast<const unsigned short*>(ws + OFF_WT4);
            const unsigned short* w4L = reinterpret_cast<const unsigned short*>(ws + OFF_WT4 + PS4);
            auto loadB4 = [&](Frag8& bh, Frag8& bl, int kc) {
                const size_t wo = (size_t)(kc * 64 + lane) * 8;   // g = 0
                bh.s = *reinterpret_cast<const short8_t*>(w4H + wo);
                bl.s = *reinterpret_cast<const short8_t*>(w4L + wo);
            };
            auto mfma4 = [&](const Frag8& bh, const Frag8& bl, int kc) {
                const int kb = 2 * kc + h;
                const int off = lds_grp(rb4 + rl, kb);
                Frag8 ah, al;
                ah.s = *reinterpret_cast<const short8_t*>(sm + off);
                al.s = *reinterpret_cast<const short8_t*>(sm + PLANE + off);
                p4 = __builtin_amdgcn_mfma_f32_32x32x16_bf16(ah.b, bh.b, p4, 0, 0, 0);
                p4 = __builtin_amdgcn_mfma_f32_32x32x16_bf16(ah.b, bl.b, p4, 0, 0, 0);
                p4 = __builtin_amdgcn_mfma_f32_32x32x16_bf16(al.b, bh.b, p4, 0, 0, 0);
            };
            Frag8 b4hA, b4lA, b4hB, b4lB;
            loadB4(b4hA, b4lA, 0);
            #pragma unroll
            for (int t = 0; t < 8; ++t) {
                loadB4(b4hB, b4lB, 2 * t + 1);
                mfma4(b4hA, b4lA, 2 * t);
                if (2 * t + 2 < 16) loadB4(b4hA, b4lA, 2 * t + 2);
                mfma4(b4hB, b4lB, 2 * t + 1);
            }
            const float* wtab = reinterpret_cast<const float*>(sm + LDS_WT);
            #pragma unroll
            for (int reg = 0; reg < 16; ++reg) {
                const int rloc = (reg & 3) + 8 * (reg >> 2) + 4 * h;
                oacc[reg] += p4[reg] * wtab[s * TM + rb4 + rloc];
            }
        }
    }

    // ---- final store: out[b][q][c], c = lane&31 (valid 0..2) ----
    if (wid < 4) {
        const int col = lane & 31, h = lane >> 5;
        if (col < 3) {
            #pragma unroll
            for (int reg = 0; reg < 16; ++reg) {
                const int row = wid * 32 + (reg & 3) + 8 * (reg >> 2) + 4 * h;
                out[(size_t)(gq0 + row) * 3 + col] = oacc[reg];
            }
        }
    }
}

// ---------------------------------------------------------------------------
// prep kernels
// ---------------------------------------------------------------------------

// [B][C][P] -> [B][P][C], C = 128
__global__ void transpose_cp(const float* __restrict__ in, float* __restrict__ out, int P) {
    __shared__ float tile[32][33];
    const int bz = blockIdx.z;
    const int p0 = blockIdx.x * 32, c0 = blockIdx.y * 32;
    const int tx = threadIdx.x, ty = threadIdx.y;   // 32 x 8
    #pragma unroll
    for (int i = 0; i < 32; i += 8)
        tile[ty + i][tx] = in[((size_t)bz * 128 + c0 + ty + i) * P + p0 + tx];
    __syncthreads();
    #pragma unroll
    for (int i = 0; i < 32; i += 8)
        out[((size_t)bz * P + p0 + ty + i) * 128 + c0 + tx] = tile[tx][ty + i];
}

// build fragment-packed hi/lo bf16 weight planes (layer-0 rows permuted, zero padded)
// packed elem offset = ((g*(Kpad/16) + kc)*64 + h*32 + rl)*8 + j
//   g = n>>5, rl = n&31, kc = k>>4, h = (k>>3)&1, j = k&7
__global__ void prep_weights(const float* __restrict__ W0, const float* __restrict__ W1,
                             const float* __restrict__ W2, const float* __restrict__ W3,
                             const float* __restrict__ W4, char* __restrict__ ws) {
    const int l = blockIdx.y;
    const int idx = blockIdx.x * 256 + threadIdx.x;
    const int Kpad = (l == 0) ? K0P : 256;
    const int Npad = (l == 4) ? 32  : 256;
    if (idx >= Kpad * Npad) return;
    const int n = idx / Kpad;
    const int k = idx - n * Kpad;
    const int No = (l == 4) ? 3 : 256;
    const float* W = (l == 0) ? W0 : (l == 1) ? W1 : (l == 2) ? W2 : (l == 3) ? W3 : W4;
    float v = 0.0f;
    if (n < No) {
        int ko = -1;
        if (l == 0) {
            // X reorder: [q_feat(0-127), lq_feat(128-255), rel(256,257), lqc(258,259), rcell(260,261)]
            if      (k < 128) ko = k;
            else if (k < 256) ko = k + 2;     // lq_feat was at orig rows 130..257
            else if (k == 256) ko = 128;      // rel_coord h
            else if (k == 257) ko = 129;      // rel_coord w
            else if (k < 262) ko = k;         // lq_coord, rel_cell at orig 258..261
        } else if (k < 256) ko = k;
        if (ko >= 0) v = W[(size_t)ko * No + n];
    }
    size_t off, ps;
    switch (l) {
        case 0:  off = OFF_WT0; ps = PS0; break;
        case 1:  off = OFF_WT1; ps = PS1; break;
        case 2:  off = OFF_WT2; ps = PS1; break;
        case 3:  off = OFF_WT3; ps = PS1; break;
        default: off = OFF_WT4; ps = PS4; break;
    }
    const int g = n >> 5, rl = n & 31;
    const int kc = k >> 4, hbit = (k >> 3) & 1, j = k & 7;
    const size_t poff = ((size_t)((g * (Kpad >> 4) + kc) * 64 + hbit * 32 + rl)) * 8 + j;
    unsigned short hh, ll; split2(v, hh, ll);
    reinterpret_cast<unsigned short*>(ws + off)[poff]      = hh;
    reinterpret_cast<unsigned short*>(ws + off + ps)[poff] = ll;
}

// ---------------------------------------------------------------------------

extern "C" void kernel_launch(void* const* d_in, const int* in_sizes, int n_in,
                              void* d_out, int out_size, void* d_ws, size_t ws_size,
                              hipStream_t stream) {
    const float* feat  = (const float*)d_in[0];
    const float* lr    = (const float*)d_in[1];
    const float* coord = (const float*)d_in[2];
    const float* cell  = (const float*)d_in[3];
    const float* W0 = (const float*)d_in[4];  const float* b0 = (const float*)d_in[5];
    const float* W1 = (const float*)d_in[6];  const float* b1 = (const float*)d_in[7];
    const float* W2 = (const float*)d_in[8];  const float* b2 = (const float*)d_in[9];
    const float* W3 = (const float*)d_in[10]; const float* b3 = (const float*)d_in[11];
    const float* W4 = (const float*)d_in[12]; const float* b4 = (const float*)d_in[13];
    char*  ws  = (char*)d_ws;
    float* out = (float*)d_out;

    dim3 bt(32, 8);
    transpose_cp<<<dim3(Hc * Wc / 32, Cc / 32, Bc), bt, 0, stream>>>(
        feat, (float*)(ws + OFF_FEATT), Hc * Wc);
    transpose_cp<<<dim3(HLc * WLc / 32, Cc / 32, Bc), bt, 0, stream>>>(
        lr, (float*)(ws + OFF_LRT), HLc * WLc);
    prep_weights<<<dim3((K0P * 256 + 255) / 256, 5), 256, 0, stream>>>(W0, W1, W2, W3, W4, ws);

    hipFuncSetAttribute(reinterpret_cast<const void*>(liif_main),
                        hipFuncAttributeMaxDynamicSharedMemorySize, LDS_TOTAL);
    const int nblocks = (Bc * 65536) / TM;   // 1024
    liif_main<<<nblocks, THREADS, LDS_TOTAL, stream>>>(
        coord, cell, ws, b0, b1, b2, b3, b4, out);
}

// Round 9
// 1311.126 us; speedup vs baseline: 3.8387x; 3.8387x over previous
//
#include <hip/hip_runtime.h>
#include <hip/hip_bf16.h>

// ---------------------------------------------------------------------------
// LIIF query_image fused kernel for MI355X (gfx950).  Round 9.
// Split-precision bf16 MFMA (hi/lo, 3 products) ~= fp32 accuracy.
// R9 = R8 (LDS-staged weight stream, 1319us but racy) + fence hardening:
// every raw s_barrier is now sandwiched in asm-"memory" fences + sched_barrier
// so the compiler cannot hoist ds_read/ds_write across it. The barrier is
// load-bearing: weight chunks are DMA'd cooperatively (8 waves x 2KB), so a
// wave's vmcnt only covers its own slice; cross-wave visibility = barrier.
// ---------------------------------------------------------------------------

typedef __attribute__((ext_vector_type(8)))  short   short8_t;
typedef __attribute__((ext_vector_type(8)))  __bf16  bf16x8;
typedef __attribute__((ext_vector_type(16))) float   f32x16;
typedef __attribute__((ext_vector_type(4)))  float   float4_t;

union Frag8 { short8_t s; bf16x8 b; };

#define EPS_SHIFT 1e-6f
#define EPS_AREA  1e-9f

constexpr int Bc = 2, Cc = 128, Hc = 128, Wc = 128, HLc = 64, WLc = 64;
constexpr int K0P = 272;           // layer0 K padded: 262 -> 272 (17 chunks)
constexpr int TM = 64;             // queries per block
constexpr int THREADS = 512;       // 8 waves: 2(M) x 4(N)
constexpr int NKB = K0P / 8;       // 34 k-blocks of 8 in act buffer
constexpr int KBS = TM * 16;       // 1024 B per k-block per plane
constexpr int PLANE = NKB * KBS;   // 34816 B (hi plane; lo follows)
constexpr int WSLOT = 16384;       // one kc chunk: 256 cols x 16 k x 2B x 2 planes
constexpr int NCHUNK = 65;         // 17 + 16*3 stream chunks (L0..L3)
constexpr int LDS_WDB  = 2 * PLANE;            // 69632: weight dbuf (4 slots)
constexpr int LDS_WTAB = LDS_WDB + 4 * WSLOT;  // 135168
constexpr int LDS_TOTAL = LDS_WTAB + 4 * TM * 4; // 136192

// workspace layout
constexpr size_t OFF_FEATT = 0;
constexpr size_t SZ_FEATT  = (size_t)Bc * Hc * Wc * Cc * 4;    // 16 MB
constexpr size_t OFF_LRT   = OFF_FEATT + SZ_FEATT;
constexpr size_t SZ_LRT    = (size_t)Bc * HLc * WLc * Cc * 4;  // 4 MB
constexpr size_t OFF_WSTR  = OFF_LRT + SZ_LRT;                 // 65 x 16KB stream
constexpr size_t SZ_WSTR   = (size_t)NCHUNK * WSLOT;
constexpr size_t OFF_W4    = OFF_WSTR + SZ_WSTR;               // L4 hi 16K + lo 16K

// ---------------------------------------------------------------------------

__device__ __forceinline__ unsigned short bf16_rne(float x) {
    unsigned u = __float_as_uint(x);
    unsigned r = (u + 0x7FFFu + ((u >> 16) & 1u)) >> 16;
    return (unsigned short)r;
}

__device__ __forceinline__ void split2(float v, unsigned short& hi, unsigned short& lo) {
    unsigned u = __float_as_uint(v) & 0xFFFF0000u;
    hi = (unsigned short)(u >> 16);
    lo = bf16_rne(v - __uint_as_float(u));
}

__device__ __forceinline__ int lds_grp(int row, int kb) {
    return kb * KBS + ((row * 16) ^ ((kb & 7) << 4));
}

template <int N>
__device__ __forceinline__ void wait_vm() {
    if constexpr (N == 4)      asm volatile("s_waitcnt vmcnt(4)" ::: "memory");
    else if constexpr (N == 2) asm volatile("s_waitcnt vmcnt(2)" ::: "memory");
    else                       asm volatile("s_waitcnt vmcnt(0)" ::: "memory");
}

// barrier with full compiler fencing: no memory op may cross (IR or MIR level).
__device__ __forceinline__ void fence_barrier() {
    asm volatile("" ::: "memory");
    __builtin_amdgcn_sched_barrier(0);
    __builtin_amdgcn_s_barrier();
    asm volatile("" ::: "memory");
    __builtin_amdgcn_sched_barrier(0);
}

__device__ __forceinline__ void async16(const char* g, char* l) {
    __builtin_amdgcn_global_load_lds(
        (const __attribute__((address_space(1))) unsigned int*)g,
        (__attribute__((address_space(3))) unsigned int*)l, 16, 0, 0);
}

// nearest-gather index math, exactly mirroring the reference formulas
__device__ __forceinline__ void calc_idx(float c0, float c1, int s,
                                         int& iy, int& ix, int& liy, int& lix,
                                         float& rel0, float& rel1) {
    const float rx = 1.0f / Hc, ry = 1.0f / Wc;
    const float vx = (s & 2) ? 1.0f : -1.0f;
    const float vy = (s & 1) ? 1.0f : -1.0f;
    const float sh0 = vx * rx + EPS_SHIFT;
    const float sh1 = vy * ry + EPS_SHIFT;
    float cc0 = fminf(fmaxf(c0 + sh0, -1.0f + 1e-6f), 1.0f - 1e-6f);
    float cc1 = fminf(fmaxf(c1 + sh1, -1.0f + 1e-6f), 1.0f - 1e-6f);
    iy  = min(max((int)floorf(((cc0 + 1.0f) * (float)Hc  - 1.0f) * 0.5f + 0.5f), 0), Hc  - 1);
    ix  = min(max((int)floorf(((cc1 + 1.0f) * (float)Wc  - 1.0f) * 0.5f + 0.5f), 0), Wc  - 1);
    liy = min(max((int)floorf(((cc0 + 1.0f) * (float)HLc - 1.0f) * 0.5f + 0.5f), 0), HLc - 1);
    lix = min(max((int)floorf(((cc1 + 1.0f) * (float)WLc - 1.0f) * 0.5f + 0.5f), 0), WLc - 1);
    const float qc0 = -1.0f + (2.0f * (float)iy + 1.0f) / (float)Hc;
    const float qc1 = -1.0f + (2.0f * (float)ix + 1.0f) / (float)Wc;
    rel0 = (c0 - qc0) * (float)Hc;
    rel1 = (c1 - qc1) * (float)Wc;
}

// gather NG*8 contiguous channels (NHWC) -> hi/lo planes at k-blocks kbBase..
template <int NG>
__device__ __forceinline__ void gather_write(const float* __restrict__ src,
                                             char* sm, int row, int kbBase) {
    #pragma unroll
    for (int g = 0; g < NG; ++g) {
        float4_t v0 = *reinterpret_cast<const float4_t*>(src + g * 8);
        float4_t v1 = *reinterpret_cast<const float4_t*>(src + g * 8 + 4);
        short8_t h8, l8;
        #pragma unroll
        for (int j = 0; j < 4; ++j) {
            unsigned short hh, ll; split2(v0[j], hh, ll);
            h8[j] = (short)hh; l8[j] = (short)ll;
        }
        #pragma unroll
        for (int j = 0; j < 4; ++j) {
            unsigned short hh, ll; split2(v1[j], hh, ll);
            h8[4 + j] = (short)hh; l8[4 + j] = (short)ll;
        }
        const int off = lds_grp(row, kbBase + g);
        *reinterpret_cast<short8_t*>(sm + off)         = h8;
        *reinterpret_cast<short8_t*>(sm + PLANE + off) = l8;
    }
}

// one pipeline phase: wait counted vmcnt -> fenced barrier -> ds_read frags ->
// issue DMA for chunk kc+3 -> 6 MFMA.
template <int WAITN, int CBASE>
__device__ __forceinline__ void phase_step(const char* sm, char* smw,
                                           const char* __restrict__ wstream,
                                           int kc, int lane, int wid, int rbase, int wn,
                                           f32x16 acc[2]) {
    const int rl = lane & 31, h = lane >> 5;
    wait_vm<WAITN>();
    fence_barrier();
    const int slot = (CBASE + kc) & 3;
    const char* wslot = smw + slot * WSLOT;
    Frag8 bh[2], bl[2], ah, al;
    #pragma unroll
    for (int ni = 0; ni < 2; ++ni) {
        const int g = wn * 2 + ni;
        bh[ni].s = *reinterpret_cast<const short8_t*>(wslot + ((g * 2 + 0) * 64 + lane) * 16);
        bl[ni].s = *reinterpret_cast<const short8_t*>(wslot + ((g * 2 + 1) * 64 + lane) * 16);
    }
    const int kb = 2 * kc + h;
    const int aoff = lds_grp(rbase + rl, kb);
    ah.s = *reinterpret_cast<const short8_t*>(sm + aoff);
    al.s = *reinterpret_cast<const short8_t*>(sm + PLANE + aoff);
    const int cnext = CBASE + kc + 3;
    if (cnext < NCHUNK) {                       // uniform branch
        const int islot = cnext & 3;
        const char* gsrc = wstream + (size_t)cnext * WSLOT + wid * 1024 + lane * 16;
        char* ldst = smw + islot * WSLOT + wid * 1024;   // wave-uniform dest base
        async16(gsrc, ldst);
        async16(gsrc + 8192, ldst + 8192);
    }
    __builtin_amdgcn_s_setprio(1);
    #pragma unroll
    for (int ni = 0; ni < 2; ++ni) {
        acc[ni] = __builtin_amdgcn_mfma_f32_32x32x16_bf16(ah.b, bh[ni].b, acc[ni], 0, 0, 0);
        acc[ni] = __builtin_amdgcn_mfma_f32_32x32x16_bf16(ah.b, bl[ni].b, acc[ni], 0, 0, 0);
        acc[ni] = __builtin_amdgcn_mfma_f32_32x32x16_bf16(al.b, bh[ni].b, acc[ni], 0, 0, 0);
    }
    __builtin_amdgcn_s_setprio(0);
}

template <int NKC, int CBASE, bool LAST>
__device__ __forceinline__ void layer_staged(const char* sm, char* smw,
                                             const char* __restrict__ wstream,
                                             int lane, int wid, int rbase, int wn,
                                             const float* __restrict__ bias, f32x16 acc[2]) {
    const int rl = lane & 31;
    #pragma unroll
    for (int ni = 0; ni < 2; ++ni) {
        const float bv = bias[wn * 64 + ni * 32 + rl];
        f32x16 a;
        #pragma unroll
        for (int i = 0; i < 16; ++i) a[i] = bv;
        acc[ni] = a;
    }
    constexpr int NMAIN = LAST ? NKC - 2 : NKC;
    #pragma unroll 4
    for (int kc = 0; kc < NMAIN; ++kc)
        phase_step<4, CBASE>(sm, smw, wstream, kc, lane, wid, rbase, wn, acc);
    if constexpr (LAST) {
        phase_step<2, CBASE>(sm, smw, wstream, NKC - 2, lane, wid, rbase, wn, acc);
        phase_step<0, CBASE>(sm, smw, wstream, NKC - 1, lane, wid, rbase, wn, acc);
    }
    fence_barrier();   // all act reads done before store_act (fenced!)
}

// relu + split + store accumulators back into the act buffer
__device__ __forceinline__ void store_act(char* sm, int lane, int rbase, int nb,
                                          const f32x16 acc[2]) {
    const int rl = lane & 31, h = lane >> 5;
    #pragma unroll
    for (int ni = 0; ni < 2; ++ni) {
        const int k   = nb + ni * 32 + rl;
        const int kbb = k >> 3;
        const int sub = (k & 7) * 2;
        const int swz = (kbb & 7) << 4;
        #pragma unroll
        for (int reg = 0; reg < 16; ++reg) {
            float v = fmaxf(acc[ni][reg], 0.0f);
            const int row = rbase + (reg & 3) + 8 * (reg >> 2) + 4 * h;
            const int off = kbb * KBS + ((row * 16) ^ swz) + sub;
            unsigned short hh, ll; split2(v, hh, ll);
            *reinterpret_cast<unsigned short*>(sm + off)         = hh;
            *reinterpret_cast<unsigned short*>(sm + PLANE + off) = ll;
        }
    }
}

// ---------------------------------------------------------------------------

__global__ __launch_bounds__(THREADS, 1)
void liif_main(const float* __restrict__ coord, const float* __restrict__ cell,
               const char* __restrict__ ws,
               const float* __restrict__ b0, const float* __restrict__ b1,
               const float* __restrict__ b2, const float* __restrict__ b3,
               const float* __restrict__ b4, float* __restrict__ out) {
    extern __shared__ char sm[];
    char* smw = sm + LDS_WDB;
    const int tid  = threadIdx.x;
    const int lane = tid & 63;
    const int wid  = tid >> 6;
    const int wm   = wid >> 2, wn = wid & 3;     // 2(M) x 4(N)
    const int rbase = wm * 32;
    const int nb    = wn * 64;
    const int gq0  = blockIdx.x * TM;
    const int bb   = gq0 >> 16;                  // batch (Q = 65536)

    const float* featT = reinterpret_cast<const float*>(ws + OFF_FEATT);
    const float* lrT   = reinterpret_cast<const float*>(ws + OFF_LRT);
    const char*  wstream = ws + OFF_WSTR;

    // ---- prologue: zero K-pad block (kb 33) + ensemble weights ----
    for (int i = tid; i < (KBS / 4) * 2; i += THREADS) {
        const int p = i / (KBS / 4);
        const int j = i - p * (KBS / 4);
        *reinterpret_cast<int*>(sm + p * PLANE + 33 * KBS + j * 4) = 0;
    }
    if (tid < TM) {
        const int gq = gq0 + tid;
        const float c0 = coord[2 * gq], c1 = coord[2 * gq + 1];
        float a[4];
        #pragma unroll
        for (int s = 0; s < 4; ++s) {
            int iy, ix, liy, lix; float r0, r1;
            calc_idx(c0, c1, s, iy, ix, liy, lix, r0, r1);
            a[s] = fabsf(r0 * r1) + EPS_AREA;
        }
        const float tot = a[0] + a[1] + a[2] + a[3];
        float* wtab = reinterpret_cast<float*>(sm + LDS_WTAB);
        #pragma unroll
        for (int s = 0; s < 4; ++s) wtab[s * TM + tid] = a[3 - s] / tot;  // diagonal swap
    }
    __syncthreads();

    f32x16 oacc;
    #pragma unroll
    for (int i = 0; i < 16; ++i) oacc[i] = 0.0f;

    #pragma unroll 1
    for (int s = 0; s < 4; ++s) {
        if (s) __syncthreads();   // prev-shift L4 act reads done before overwrite

        // ---- issue weight-stream prologue (chunks 0..2) before gather ----
        #pragma unroll
        for (int c = 0; c < 3; ++c) {
            const char* gsrc = wstream + (size_t)c * WSLOT + wid * 1024 + lane * 16;
            char* ldst = smw + c * WSLOT + wid * 1024;
            async16(gsrc, ldst);
            async16(gsrc + 8192, ldst + 8192);
        }

        // ---- gather: build X tile (262-dim, reordered) in hi/lo planes ----
        {
            const int r = tid >> 3, p = tid & 7;   // 8 threads/row, 16 ch each
            const int gq = gq0 + r;
            const float c0 = coord[2 * gq], c1 = coord[2 * gq + 1];
            int iy, ix, liy, lix; float r0, r1;
            calc_idx(c0, c1, s, iy, ix, liy, lix, r0, r1);
            const float* fsrc = featT + (((size_t)(bb * Hc  + iy)  * Wc  + ix)  * Cc + p * 16);
            const float* lsrc = lrT   + (((size_t)(bb * HLc + liy) * WLc + lix) * Cc + p * 16);
            gather_write<2>(fsrc, sm, r, p * 2);        // q_feat  -> k 0..127
            gather_write<2>(lsrc, sm, r, 16 + p * 2);   // lq_feat -> k 128..255
            if (tid < TM) {                             // extras  -> kb 32
                const int gq2 = gq0 + tid;
                const float d0 = coord[2 * gq2], d1 = coord[2 * gq2 + 1];
                int jy, jx, ljy, ljx; float s0, s1;
                calc_idx(d0, d1, s, jy, jx, ljy, ljx, s0, s1);
                float vals[8];
                vals[0] = s0;
                vals[1] = s1;
                vals[2] = -1.0f + (2.0f * (float)ljy + 1.0f) / (float)HLc;
                vals[3] = -1.0f + (2.0f * (float)ljx + 1.0f) / (float)WLc;
                vals[4] = cell[2 * gq2]     * (float)Hc;
                vals[5] = cell[2 * gq2 + 1] * (float)Wc;
                vals[6] = 0.0f; vals[7] = 0.0f;
                short8_t h8, l8;
                #pragma unroll
                for (int j = 0; j < 8; ++j) {
                    unsigned short hh, ll; split2(vals[j], hh, ll);
                    h8[j] = (short)hh; l8[j] = (short)ll;
                }
                const int off = 32 * KBS + tid * 16;
                *reinterpret_cast<short8_t*>(sm + off)         = h8;
                *reinterpret_cast<short8_t*>(sm + PLANE + off) = l8;
            }
        }
        // gather LDS writes visible; do NOT drain vmcnt (DMA in flight)
        asm volatile("s_waitcnt lgkmcnt(0)" ::: "memory");
        fence_barrier();

        // ---- layers 0..3 via the staged stream ----
        f32x16 acc[2];
        layer_staged<17, 0,  false>(sm, smw, wstream, lane, wid, rbase, wn, b0, acc);
        store_act(sm, lane, rbase, nb, acc);
        asm volatile("s_waitcnt lgkmcnt(0)" ::: "memory");
        fence_barrier();

        layer_staged<16, 17, false>(sm, smw, wstream, lane, wid, rbase, wn, b1, acc);
        store_act(sm, lane, rbase, nb, acc);
        asm volatile("s_waitcnt lgkmcnt(0)" ::: "memory");
        fence_barrier();

        layer_staged<16, 33, false>(sm, smw, wstream, lane, wid, rbase, wn, b2, acc);
        store_act(sm, lane, rbase, nb, acc);
        asm volatile("s_waitcnt lgkmcnt(0)" ::: "memory");
        fence_barrier();

        layer_staged<16, 49, true >(sm, smw, wstream, lane, wid, rbase, wn, b3, acc);
        store_act(sm, lane, rbase, nb, acc);
        asm volatile("s_waitcnt lgkmcnt(0)" ::: "memory");
        fence_barrier();

        // ---- layer 4 (N=3 padded to 32): waves 0..1 ----
        if (wid < 2) {
            const int rl = lane & 31, h = lane >> 5;
            const int rb4 = wid * 32;
            const float bv = (rl < 3) ? b4[rl] : 0.0f;
            f32x16 p4;
            #pragma unroll
            for (int i = 0; i < 16; ++i) p4[i] = bv;
            const unsigned short* w4H = reinterpret_cast<const unsigned short*>(ws + OFF_W4);
            const unsigned short* w4L = reinterpret_cast<const unsigned short*>(ws + OFF_W4 + WSLOT);
            #pragma unroll 2
            for (int kc = 0; kc < 16; ++kc) {
                const int kb = 2 * kc + h;
                const int off = lds_grp(rb4 + rl, kb);
                Frag8 ah, al, bh, bl;
                ah.s = *reinterpret_cast<const short8_t*>(sm + off);
                al.s = *reinterpret_cast<const short8_t*>(sm + PLANE + off);
                const size_t wo = (size_t)(kc * 64 + lane) * 8;
                bh.s = *reinterpret_cast<const short8_t*>(w4H + wo);
                bl.s = *reinterpret_cast<const short8_t*>(w4L + wo);
                p4 = __builtin_amdgcn_mfma_f32_32x32x16_bf16(ah.b, bh.b, p4, 0, 0, 0);
                p4 = __builtin_amdgcn_mfma_f32_32x32x16_bf16(ah.b, bl.b, p4, 0, 0, 0);
                p4 = __builtin_amdgcn_mfma_f32_32x32x16_bf16(al.b, bh.b, p4, 0, 0, 0);
            }
            const float* wtab = reinterpret_cast<const float*>(sm + LDS_WTAB);
            #pragma unroll
            for (int reg = 0; reg < 16; ++reg) {
                const int rloc = (reg & 3) + 8 * (reg >> 2) + 4 * h;
                oacc[reg] += p4[reg] * wtab[s * TM + rb4 + rloc];
            }
        }
    }

    // ---- final store: out[b][q][c] ----
    if (wid < 2) {
        const int col = lane & 31, h = lane >> 5;
        if (col < 3) {
            #pragma unroll
            for (int reg = 0; reg < 16; ++reg) {
                const int row = wid * 32 + (reg & 3) + 8 * (reg >> 2) + 4 * h;
                out[(size_t)(gq0 + row) * 3 + col] = oacc[reg];
            }
        }
    }
}

// ---------------------------------------------------------------------------
// prep kernels
// ---------------------------------------------------------------------------

// [B][C][P] -> [B][P][C], C = 128
__global__ void transpose_cp(const float* __restrict__ in, float* __restrict__ out, int P) {
    __shared__ float tile[32][33];
    const int bz = blockIdx.z;
    const int p0 = blockIdx.x * 32, c0 = blockIdx.y * 32;
    const int tx = threadIdx.x, ty = threadIdx.y;   // 32 x 8
    #pragma unroll
    for (int i = 0; i < 32; i += 8)
        tile[ty + i][tx] = in[((size_t)bz * 128 + c0 + ty + i) * P + p0 + tx];
    __syncthreads();
    #pragma unroll
    for (int i = 0; i < 32; i += 8)
        out[((size_t)bz * P + p0 + ty + i) * 128 + c0 + tx] = tile[tx][ty + i];
}

// pack weights:
//  L0..L3 -> contiguous chunk stream: chunk c = cb[l] + (k>>4), 16KB each,
//    elem offset = ((g*2+pl)*64 + h*32 + rl)*8 + j   (g=n>>5, rl=n&31,
//    h=(k>>3)&1, j=k&7) -- exactly the per-phase frag read layout.
//  L4 -> frag-packed hi/lo planes at OFF_W4.
__global__ void prep_weights(const float* __restrict__ W0, const float* __restrict__ W1,
                             const float* __restrict__ W2, const float* __restrict__ W3,
                             const float* __restrict__ W4, char* __restrict__ ws) {
    const int l = blockIdx.y;
    const int idx = blockIdx.x * 256 + threadIdx.x;
    const int Kpad = (l == 0) ? K0P : 256;
    const int Npad = (l == 4) ? 32  : 256;
    if (idx >= Kpad * Npad) return;
    const int n = idx / Kpad;
    const int k = idx - n * Kpad;
    const int No = (l == 4) ? 3 : 256;
    const float* W = (l == 0) ? W0 : (l == 1) ? W1 : (l == 2) ? W2 : (l == 3) ? W3 : W4;
    float v = 0.0f;
    if (n < No) {
        int ko = -1;
        if (l == 0) {
            if      (k < 128) ko = k;
            else if (k < 256) ko = k + 2;     // lq_feat at orig rows 130..257
            else if (k == 256) ko = 128;      // rel_coord h
            else if (k == 257) ko = 129;      // rel_coord w
            else if (k < 262) ko = k;         // lq_coord, rel_cell at 258..261
        } else if (k < 256) ko = k;
        if (ko >= 0) v = W[(size_t)ko * No + n];
    }
    unsigned short hh, ll; split2(v, hh, ll);
    const int g = n >> 5, rl = n & 31;
    const int hbit = (k >> 3) & 1, j = k & 7;
    if (l < 4) {
        const int cb = (l == 0) ? 0 : (17 + 16 * (l - 1));
        const int c  = cb + (k >> 4);
        unsigned short* ch = reinterpret_cast<unsigned short*>(ws + OFF_WSTR + (size_t)c * WSLOT);
        ch[((g * 2 + 0) * 64 + hbit * 32 + rl) * 8 + j] = hh;
        ch[((g * 2 + 1) * 64 + hbit * 32 + rl) * 8 + j] = ll;
    } else {
        const size_t poff = ((size_t)((k >> 4) * 64 + hbit * 32 + rl)) * 8 + j;
        reinterpret_cast<unsigned short*>(ws + OFF_W4)[poff]         = hh;
        reinterpret_cast<unsigned short*>(ws + OFF_W4 + WSLOT)[poff] = ll;
    }
}

// ---------------------------------------------------------------------------

extern "C" void kernel_launch(void* const* d_in, const int* in_sizes, int n_in,
                              void* d_out, int out_size, void* d_ws, size_t ws_size,
                              hipStream_t stream) {
    const float* feat  = (const float*)d_in[0];
    const float* lr    = (const float*)d_in[1];
    const float* coord = (const float*)d_in[2];
    const float* cell  = (const float*)d_in[3];
    const float* W0 = (const float*)d_in[4];  const float* b0 = (const float*)d_in[5];
    const float* W1 = (const float*)d_in[6];  const float* b1 = (const float*)d_in[7];
    const float* W2 = (const float*)d_in[8];  const float* b2 = (const float*)d_in[9];
    const float* W3 = (const float*)d_in[10]; const float* b3 = (const float*)d_in[11];
    const float* W4 = (const float*)d_in[12]; const float* b4 = (const float*)d_in[13];
    char*  ws  = (char*)d_ws;
    float* out = (float*)d_out;

    dim3 bt(32, 8);
    transpose_cp<<<dim3(Hc * Wc / 32, Cc / 32, Bc), bt, 0, stream>>>(
        feat, (float*)(ws + OFF_FEATT), Hc * Wc);
    transpose_cp<<<dim3(HLc * WLc / 32, Cc / 32, Bc), bt, 0, stream>>>(
        lr, (float*)(ws + OFF_LRT), HLc * WLc);
    prep_weights<<<dim3((K0P * 256 + 255) / 256, 5), 256, 0, stream>>>(W0, W1, W2, W3, W4, ws);

    hipFuncSetAttribute(reinterpret_cast<const void*>(liif_main),
                        hipFuncAttributeMaxDynamicSharedMemorySize, LDS_TOTAL);
    const int nblocks = (Bc * 65536) / TM;   // 2048
    liif_main<<<nblocks, THREADS, LDS_TOTAL, stream>>>(
        coord, cell, ws, b0, b1, b2, b3, b4, out);
}